// Round 16
// baseline (78.395 us; speedup 1.0000x reference)
//
#include <hip/hip_runtime.h>
#include <hip/hip_bf16.h>

// Wide_BasicBlock_Q: DoReFa-quantized residual block on MI355X (gfx950).
// Round 16: quarter-image mega blocks — TLP x ILP balance.
//   - 1024 blocks (image n, quarter Q: out rows H0=Q*4..+3), 512 thr / 8 waves
//   - LDS 50,304B: slab[13][34][64] i8 + a2p[6][18][128] i8 + asc[4][16][64]
//     -> 3 blocks/CU (24 waves/CU) at __launch_bounds__(512,6) (~84 VGPR)
//   - P1: x rows 2H0-3..2H0+9 (13 slots, out-of-range -> zeros) -> slab; asc
//   - P2: conv1 -> a2p rows H0-1..H0+4 (24 asgn of 32co x 1row, 3/wave);
//     outside rows (a2 -1/16) stored as zeros (r13 fix)
//   - P3: conv2 (wave=32co x 32pos) + bf16 shortcut -> fp32 NCHW out
//   - explicit depth-1 weight ping-pong (named regs); P3 s=0 weights loaded
//     pre-barrier; XCD-bijective block swizzle (quarters share L2)

typedef __bf16 bf16x8 __attribute__((ext_vector_type(8)));
typedef float f32x4 __attribute__((ext_vector_type(4)));
typedef int i32x4 __attribute__((ext_vector_type(4)));

#define EPSV 1e-5f

// per-block partial max|w| -> wpart[b] (plain store, deterministic)
__global__ __launch_bounds__(256) void k_wmax(const float* __restrict__ w1,
                                              const float* __restrict__ w2,
                                              float* __restrict__ wpart) {
    int sel = blockIdx.x >> 4;                 // 0: w1, 1: w2
    const float* src = sel ? w2 : w1;
    int cnt = sel ? 128 * 128 * 9 : 128 * 64 * 9;
    float m = 0.f;
    for (int i = (blockIdx.x & 15) * 256 + threadIdx.x; i < cnt; i += 16 * 256)
        m = fmaxf(m, fabsf(src[i]));
#pragma unroll
    for (int off = 32; off > 0; off >>= 1)
        m = fmaxf(m, __shfl_down(m, off));
    __shared__ float red[4];
    if ((threadIdx.x & 63) == 0) red[threadIdx.x >> 6] = m;
    __syncthreads();
    if (threadIdx.x == 0)
        wpart[blockIdx.x] = fmaxf(fmaxf(red[0], red[1]), fmaxf(red[2], red[3]));
}

// bnp layout (floats): [0:64)=sc1 [64:128)=sh1 [128:192)=scs [192:256)=shs
// [256:384)=sc2 [384:512)=sh2 [512]=c1 [513]=c2  (c = 15/(2 tanh(max|w|)))
__global__ void k_bnprep(const float* g1, const float* b1, const float* m1, const float* v1,
                         const float* g2, const float* b2, const float* m2, const float* v2,
                         const float* gs, const float* bs, const float* ms, const float* vs,
                         const float* __restrict__ wpart, float* bnp) {
    int c = threadIdx.x;  // blockDim = 128
    if (c < 64) {
        float s = g1[c] * rsqrtf(v1[c] + EPSV);
        bnp[c] = s;          bnp[64 + c] = b1[c] - m1[c] * s;
        float s2 = gs[c] * rsqrtf(vs[c] + EPSV);
        bnp[128 + c] = s2;   bnp[192 + c] = bs[c] - ms[c] * s2;
    }
    float s = g2[c] * rsqrtf(v2[c] + EPSV);
    bnp[256 + c] = s;        bnp[384 + c] = b2[c] - m2[c] * s;
    if (c < 2) {
        float m = 0.f;
#pragma unroll
        for (int i = 0; i < 16; ++i) m = fmaxf(m, wpart[c * 16 + i]);
        bnp[512 + c] = 15.f / (2.f * tanhf(m));
    }
}

// All weight packs in one dispatch (grid 896):
//  b<288 : w1 -> i8 [(s*128+co)*64+kk], k=s*64+kk, k-order khw*64+ci
//  b<864 : w2 -> i8 same with CIN=128
//  else  : wsw -> bf16 [(s*128+co)*32+kk] (1x1: k=ci), unquantized
__global__ __launch_bounds__(256) void k_wq_all(
        const float* __restrict__ w1, const float* __restrict__ w2,
        const float* __restrict__ wsw,
        signed char* __restrict__ w1qi, signed char* __restrict__ w2qi,
        __bf16* __restrict__ wsq, const float* __restrict__ bnp) {
    int b = blockIdx.x, t = threadIdx.x;
    if (b < 864) {
        bool isw1 = b < 288;
        int idx = (isw1 ? b : b - 288) * 256 + t;
        float c = bnp[512 + (isw1 ? 0 : 1)];
        int kk = idx & 63;
        int co = (idx >> 6) & 127;
        int s = idx >> 13;
        int k = s * 64 + kk;
        int khw, ci;
        const float* src;
        if (isw1) { khw = k >> 6; ci = k & 63;  src = w1 + (co * 64 + ci) * 9 + khw; }
        else      { khw = k >> 7; ci = k & 127; src = w2 + (co * 128 + ci) * 9 + khw; }
        int j = (int)rintf(tanhf(*src) * c + 7.5f);
        (isw1 ? w1qi : w2qi)[idx] = (signed char)(2 * j - 15);
    } else {
        int idx = (b - 864) * 256 + t;
        int kk = idx & 31;
        int co = (idx >> 5) & 127;
        int s = idx >> 12;
        wsq[idx] = (__bf16)wsw[co * 64 + s * 32 + kk];
    }
}

// ---- mega kernel: one quarter-image per block (1024 blocks, 3/CU) ----
__global__ __launch_bounds__(512, 6) void k_mega(
        const float* __restrict__ x,
        const signed char* __restrict__ w1qi,
        const signed char* __restrict__ w2qi,
        const __bf16* __restrict__ wsq,
        const float* __restrict__ bnp,
        float* __restrict__ out) {
    // LDS: slab 13*34*64 = 28288 | a2p 6*18*128 = 13824 | asc 4*16*64*2 = 8192
    __shared__ __align__(16) char lds_all[28288 + 13824 + 8192];
    signed char* slab = (signed char*)lds_all;
    signed char* a2p  = (signed char*)(lds_all + 28288);
    char*        ascb = lds_all + 28288 + 13824;

    const int t = threadIdx.x;
    // XCD-bijective swizzle (1024 % 8 == 0): each XCD gets 128 consecutive
    // logical blocks = 32 whole images -> quarters share the XCD's L2.
    const int wg = (int)blockIdx.x;
    const int lb = (wg & 7) * 128 + (wg >> 3);
    const int n = lb >> 2;
    const int H0 = (lb & 3) * 4;             // out rows H0..H0+3
    const int r0s = 2 * H0 - 3;              // slab row 0 = x row r0s
    const int wv = t >> 6, l = t & 63;
    const int lrow = l & 15, quad = l >> 4;

    // ---- P1a: zero vertical borders (cols 0, 33 / 0, 17) ----
    if (t < 104) {                           // slab: 26 cells x 4 chunks
        int ci_ = t >> 2, sub = t & 3;
        int row = ci_ >> 1, col = (ci_ & 1) * 33;
        *(uint4*)(slab + (row * 34 + col) * 64 + sub * 16) = uint4{0u, 0u, 0u, 0u};
    }
    if (t < 96) {                            // a2p: 12 cells x 8 chunks
        int ci_ = t >> 3, sub = t & 7;
        int row = ci_ >> 1, col = (ci_ & 1) * 17;
        *(uint4*)(a2p + (row * 18 + col) * 128 + sub * 16) = uint4{0u, 0u, 0u, 0u};
    }

    // ---- P1b: x rows r0s..r0s+12 -> bn1+actq -> slab; bn_s -> asc ----
    // unit u: cq = u/104 (4 ch), sr = (u%104)>>3 (slab row), w0 = (u&7)*4
#pragma unroll
    for (int it = 0; it < 4; ++it) {
        int u = t + it * 512;
        if (u < 1664) {
            int cq = u / 104;
            int rem = u - cq * 104;
            int sr = rem >> 3, w0 = (rem & 7) * 4;
            int hx = r0s + sr;
            bool valid = (unsigned)hx < 32u;
            int c0 = cq * 4;
            float4 xr[4];
            if (valid) {
#pragma unroll
                for (int j = 0; j < 4; ++j)
                    xr[j] = *(const float4*)(x + ((size_t)(n * 64 + c0 + j)) * 1024 + hx * 32 + w0);
            }
            float4 s1 = *(const float4*)(bnp + c0);
            float4 h1 = *(const float4*)(bnp + 64 + c0);
            const float* s1p = (const float*)&s1;
            const float* h1p = (const float*)&h1;
#pragma unroll
            for (int k = 0; k < 4; ++k) {
                unsigned u32 = 0;
                if (valid) {
#pragma unroll
                    for (int j = 0; j < 4; ++j) {
                        float xv = ((const float*)&xr[j])[k];
                        float v = xv * s1p[j] + h1p[j];
                        int q = (int)rintf(fminf(fmaxf(v, 0.f), 1.f) * 15.f);
                        u32 |= (unsigned)q << (8 * j);
                    }
                }
                int pw = w0 + k + 1;
                int cell = sr * 34 + pw;
                int key = (pw >> 1) & 3;
                *(unsigned*)(slab + cell * 64 + (((cq >> 2) ^ key) * 16) + (cq & 3) * 4) = u32;
            }
            if (valid && ((hx & 1) == 0) && ((unsigned)(hx - 2 * H0) < 8u)) {
                float4 ssv = *(const float4*)(bnp + 128 + c0);
                float4 hsv = *(const float4*)(bnp + 192 + c0);
                const float* ssp = (const float*)&ssv;
                const float* hsp = (const float*)&hsv;
                int h2l = (hx >> 1) - H0;    // 0..3
#pragma unroll
                for (int k = 0; k < 4; k += 2) {
                    int w = w0 + k;
                    __bf16 bv[4];
#pragma unroll
                    for (int j = 0; j < 4; ++j) {
                        float xv = ((const float*)&xr[j])[k];
                        bv[j] = (__bf16)(xv * ssp[j] + hsp[j]);
                    }
                    int cell = h2l * 16 + (w >> 1);
                    int key = (w >> 1) & 7;
                    *(uint2*)(ascb + cell * 128 + (((cq >> 1) ^ key) * 16) + (cq & 1) * 8) =
                        *(uint2*)bv;
                }
            }
        }
    }
    __syncthreads();

    // ---- P2: conv1 (3x3 s2 p1) -> a2p rows H0-1..H0+4 (local lr 0..5) ----
    // 24 assignments (coT = a&3: 32 co; lr = a>>2), 3 per wave.
    auto ldW1 = [&](int s, int coT, i32x4* dst) {
#pragma unroll
        for (int i = 0; i < 2; ++i)
            dst[i] = *(const i32x4*)(w1qi +
                ((s * 128 + coT * 32 + i * 16 + lrow) * 64 + quad * 16));
    };
#pragma unroll 1
    for (int pass = 0; pass < 3; ++pass) {
        const int a = wv + pass * 8;
        const int coT = a & 3, lr = a >> 2;
        const int ag = H0 - 1 + lr;                  // global a2 row
        const bool outside = (unsigned)ag > 15u;     // conv2 zero-padding row
        i32x4 acc1[2] = {};
        if (!outside) {
            i32x4 afA[2], afB[2];
            ldW1(0, coT, afA);
            auto p2step = [&](int s, i32x4* af) {
                const int kh = (s * 11) >> 5;        // s/3, s<9
                const int kw = s - 3 * kh;
                const int sr = 2 * lr + kh;          // always in [0,12]
                const int pw = 2 * lrow + kw;
                const int key = (pw >> 1) & 3;
                i32x4 bf = *(const i32x4*)(slab + (sr * 34 + pw) * 64 + ((quad ^ key) * 16));
#pragma unroll
                for (int i = 0; i < 2; ++i)
                    acc1[i] = __builtin_amdgcn_mfma_i32_16x16x64_i8(af[i], bf, acc1[i], 0, 0, 0);
            };
#pragma unroll 1
            for (int sp = 0; sp < 4; ++sp) {
                ldW1(2 * sp + 1, coT, afB);
                p2step(2 * sp, afA);
                ldW1(2 * sp + 2, coT, afA);          // max s = 8
                p2step(2 * sp + 1, afB);
            }
            p2step(8, afA);
        }
        // epilogue: bn2+actq -> a2p (zeros for outside padding rows)
#pragma unroll
        for (int i = 0; i < 2; ++i) {
            const int co0 = coT * 32 + i * 16 + quad * 4;
            unsigned u32 = 0;
            if (!outside) {
                float4 s2 = *(const float4*)(bnp + 256 + co0);
                float4 h2f = *(const float4*)(bnp + 384 + co0);
                const float* s2p = (const float*)&s2;
                const float* h2p = (const float*)&h2f;
#pragma unroll
                for (int r = 0; r < 4; ++r) {
                    float v = (float)acc1[i][r] * (s2p[r] * (1.f / 225.f)) + h2p[r];
                    int q = (int)rintf(fminf(fmaxf(v, 0.f), 1.f) * 15.f);
                    u32 |= (unsigned)q << (8 * r);
                }
            }
            int cell = lr * 18 + (lrow + 1);
            int key = (lrow + 1) & 7;
            *(unsigned*)(a2p + cell * 128 + (((co0 >> 4) ^ key) * 16) + (co0 & 15)) = u32;
        }
    }

    // ---- P3: conv2 (3x3 s1 p1, 18 K64-steps) + bf16 shortcut -> out ----
    const int wco = wv & 3, wp = wv >> 2;    // 4 co-tiles(32) x 2 pos-tiles(2 rows)
    auto ldW2 = [&](int s, i32x4* dst) {
#pragma unroll
        for (int i = 0; i < 2; ++i)
            dst[i] = *(const i32x4*)(w2qi +
                ((s * 128 + wco * 32 + i * 16 + lrow) * 64 + quad * 16));
    };
    i32x4 af3A[2], af3B[2];
    ldW2(0, af3A);                            // issued BEFORE the barrier
    __syncthreads();
    {
        i32x4 acc2[2][2] = {};
        auto p3step = [&](int s, i32x4* af) {
            const int khw = s >> 1, cis = s & 1;
            const int kh = (khw * 11) >> 5;   // khw/3, khw<9
            const int kw = khw - 3 * kh;
            i32x4 bf[2];
#pragma unroll
            for (int j = 0; j < 2; ++j) {
                int lr3 = wp * 2 + j + kh;               // local a2p row 0..5
                int pw = lrow + kw;                      // padded col 0..17
                int chunk = cis * 4 + quad;
                int key = pw & 7;
                bf[j] = *(const i32x4*)(a2p + (lr3 * 18 + pw) * 128 + ((chunk ^ key) * 16));
            }
#pragma unroll
            for (int i = 0; i < 2; ++i)
#pragma unroll
                for (int j = 0; j < 2; ++j)
                    acc2[i][j] = __builtin_amdgcn_mfma_i32_16x16x64_i8(af[i], bf[j], acc2[i][j], 0, 0, 0);
        };
#pragma unroll 1
        for (int sp = 0; sp < 9; ++sp) {
            ldW2(2 * sp + 1, af3B);
            p3step(2 * sp, af3A);
            ldW2(sp < 8 ? 2 * sp + 2 : 16, af3A);
            p3step(2 * sp + 1, af3B);
        }
        f32x4 accM[2][2];
#pragma unroll
        for (int i = 0; i < 2; ++i)
#pragma unroll
            for (int j = 0; j < 2; ++j)
#pragma unroll
                for (int r = 0; r < 4; ++r)
                    accM[i][j][r] = (float)acc2[i][j][r] * (1.f / 225.f);
        // shortcut: 2 bf16 K32-steps from asc, C-in = accM
#pragma unroll
        for (int s = 0; s < 2; ++s) {
            bf16x8 af[2], bb[2];
#pragma unroll
            for (int i = 0; i < 2; ++i)
                af[i] = *(const bf16x8*)(wsq + (size_t)s * 4096 +
                    ((wco * 32 + i * 16 + lrow) * 32 + quad * 8));
#pragma unroll
            for (int j = 0; j < 2; ++j) {
                int cell = (wp * 2 + j) * 16 + lrow;
                int sub = s * 4 + quad;
                bb[j] = *(const bf16x8*)(ascb + cell * 128 + ((sub ^ (lrow & 7)) * 16));
            }
#pragma unroll
            for (int i = 0; i < 2; ++i)
#pragma unroll
                for (int j = 0; j < 2; ++j)
                    accM[i][j] = __builtin_amdgcn_mfma_f32_16x16x32_bf16(af[i], bb[j], accM[i][j], 0, 0, 0);
        }
        // store out fp32 NCHW
#pragma unroll
        for (int i = 0; i < 2; ++i) {
            const int co0 = wco * 32 + i * 16 + quad * 4;
#pragma unroll
            for (int j = 0; j < 2; ++j) {
                int pos = (H0 + wp * 2 + j) * 16 + lrow;
#pragma unroll
                for (int r = 0; r < 4; ++r)
                    out[((size_t)n * 128 + co0 + r) * 256 + pos] = accM[i][j][r];
            }
        }
    }
}

extern "C" void kernel_launch(void* const* d_in, const int* in_sizes, int n_in,
                              void* d_out, int out_size, void* d_ws, size_t ws_size,
                              hipStream_t stream) {
    const float* x   = (const float*)d_in[0];
    const float* w1  = (const float*)d_in[1];
    const float* w2  = (const float*)d_in[2];
    const float* wsw = (const float*)d_in[3];
    const float* g1  = (const float*)d_in[4];
    const float* b1  = (const float*)d_in[5];
    const float* m1  = (const float*)d_in[6];
    const float* v1  = (const float*)d_in[7];
    const float* g2  = (const float*)d_in[8];
    const float* b2  = (const float*)d_in[9];
    const float* m2  = (const float*)d_in[10];
    const float* v2  = (const float*)d_in[11];
    const float* gs  = (const float*)d_in[12];
    const float* bs  = (const float*)d_in[13];
    const float* ms  = (const float*)d_in[14];
    const float* vs  = (const float*)d_in[15];
    float* out = (float*)d_out;
    char* ws = (char*)d_ws;

    // ws layout (bytes), ~256 KB total
    signed char* w1qi = (signed char*)(ws);                 // 73,728 i8
    signed char* w2qi = (signed char*)(ws + 73728);         // 147,456 i8
    __bf16*      wsq  = (__bf16*)(ws + 221184);             // 8,192 bf16
    float*       bnp  = (float*)(ws + 237568);              // 514 floats
    float*       wprt = (float*)(ws + 240128);              // 32 floats

    k_wmax<<<32, 256, 0, stream>>>(w1, w2, wprt);
    k_bnprep<<<1, 128, 0, stream>>>(g1, b1, m1, v1, g2, b2, m2, v2,
                                    gs, bs, ms, vs, wprt, bnp);
    k_wq_all<<<896, 256, 0, stream>>>(w1, w2, wsw, w1qi, w2qi, wsq, bnp);
    k_mega<<<1024, 512, 0, stream>>>(x, w1qi, w2qi, wsq, bnp, out);
}

// Round 18
// 57.922 us; speedup vs baseline: 1.3535x; 1.3535x over previous
//
#include <hip/hip_runtime.h>
#include <hip/hip_bf16.h>

// Wide_BasicBlock_Q: DoReFa-quantized residual block on MI355X (gfx950).
// Round 18: r10 full-image mega-kernel + non-temporal hints (r17 compile fix:
// nontemporal builtins need clang ext-vector types, not HIP float4).
//   Theory: P1's x-stream + P3's out-stream thrash the 4MB XCD L2, evicting
//   the 224KB weight set -> P2/P3 weight loads miss to HBM (~900cy), pinning
//   MfmaUtil at ~9%. nt-load x / nt-store out keeps weights L2-resident.

typedef __bf16 bf16x8 __attribute__((ext_vector_type(8)));
typedef float f32x4 __attribute__((ext_vector_type(4)));
typedef int i32x4 __attribute__((ext_vector_type(4)));

#define EPSV 1e-5f

// per-block partial max|w| -> wpart[b] (plain store, deterministic)
__global__ __launch_bounds__(256) void k_wmax(const float* __restrict__ w1,
                                              const float* __restrict__ w2,
                                              float* __restrict__ wpart) {
    int sel = blockIdx.x >> 4;                 // 0: w1, 1: w2
    const float* src = sel ? w2 : w1;
    int cnt = sel ? 128 * 128 * 9 : 128 * 64 * 9;
    float m = 0.f;
    for (int i = (blockIdx.x & 15) * 256 + threadIdx.x; i < cnt; i += 16 * 256)
        m = fmaxf(m, fabsf(src[i]));
#pragma unroll
    for (int off = 32; off > 0; off >>= 1)
        m = fmaxf(m, __shfl_down(m, off));
    __shared__ float red[4];
    if ((threadIdx.x & 63) == 0) red[threadIdx.x >> 6] = m;
    __syncthreads();
    if (threadIdx.x == 0)
        wpart[blockIdx.x] = fmaxf(fmaxf(red[0], red[1]), fmaxf(red[2], red[3]));
}

// bnp layout (floats): [0:64)=sc1 [64:128)=sh1 [128:192)=scs [192:256)=shs
// [256:384)=sc2 [384:512)=sh2 [512]=c1 [513]=c2  (c = 15/(2 tanh(max|w|)))
__global__ void k_bnprep(const float* g1, const float* b1, const float* m1, const float* v1,
                         const float* g2, const float* b2, const float* m2, const float* v2,
                         const float* gs, const float* bs, const float* ms, const float* vs,
                         const float* __restrict__ wpart, float* bnp) {
    int c = threadIdx.x;  // blockDim = 128
    if (c < 64) {
        float s = g1[c] * rsqrtf(v1[c] + EPSV);
        bnp[c] = s;          bnp[64 + c] = b1[c] - m1[c] * s;
        float s2 = gs[c] * rsqrtf(vs[c] + EPSV);
        bnp[128 + c] = s2;   bnp[192 + c] = bs[c] - ms[c] * s2;
    }
    float s = g2[c] * rsqrtf(v2[c] + EPSV);
    bnp[256 + c] = s;        bnp[384 + c] = b2[c] - m2[c] * s;
    if (c < 2) {
        float m = 0.f;
#pragma unroll
        for (int i = 0; i < 16; ++i) m = fmaxf(m, wpart[c * 16 + i]);
        bnp[512 + c] = 15.f / (2.f * tanhf(m));
    }
}

// All weight packs in one dispatch (grid 896):
//  b<288 : w1 -> i8 [(s*128+co)*64+kk], k=s*64+kk, k-order khw*64+ci
//  b<864 : w2 -> i8 same with CIN=128
//  else  : wsw -> bf16 [(s*128+co)*32+kk] (1x1: k=ci), unquantized
__global__ __launch_bounds__(256) void k_wq_all(
        const float* __restrict__ w1, const float* __restrict__ w2,
        const float* __restrict__ wsw,
        signed char* __restrict__ w1qi, signed char* __restrict__ w2qi,
        __bf16* __restrict__ wsq, const float* __restrict__ bnp) {
    int b = blockIdx.x, t = threadIdx.x;
    if (b < 864) {
        bool isw1 = b < 288;
        int idx = (isw1 ? b : b - 288) * 256 + t;
        float c = bnp[512 + (isw1 ? 0 : 1)];
        int kk = idx & 63;
        int co = (idx >> 6) & 127;
        int s = idx >> 13;
        int k = s * 64 + kk;
        int khw, ci;
        const float* src;
        if (isw1) { khw = k >> 6; ci = k & 63;  src = w1 + (co * 64 + ci) * 9 + khw; }
        else      { khw = k >> 7; ci = k & 127; src = w2 + (co * 128 + ci) * 9 + khw; }
        int j = (int)rintf(tanhf(*src) * c + 7.5f);
        (isw1 ? w1qi : w2qi)[idx] = (signed char)(2 * j - 15);
    } else {
        int idx = (b - 864) * 256 + t;
        int kk = idx & 31;
        int co = (idx >> 5) & 127;
        int s = idx >> 12;
        wsq[idx] = (__bf16)wsw[co * 64 + s * 32 + kk];
    }
}

// ---- mega kernel: one image per block ----
__global__ __launch_bounds__(1024, 4) void k_mega(
        const float* __restrict__ x,
        const signed char* __restrict__ w1qi,
        const signed char* __restrict__ w2qi,
        const __bf16* __restrict__ wsq,
        const float* __restrict__ bnp,
        float* __restrict__ out) {
    // LDS: slab 34*34*64 = 73984 | a2p 18*18*128 = 41472 | asc 256*128 = 32768
    __shared__ __align__(16) char lds_all[73984 + 41472 + 32768];
    signed char* slab = (signed char*)lds_all;
    signed char* a2p  = (signed char*)(lds_all + 73984);
    char*        ascb = lds_all + 73984 + 41472;

    const int t = threadIdx.x;
    const int n = blockIdx.x;
    const int wv = t >> 6, l = t & 63;
    const int lrow = l & 15, quad = l >> 4;

    // ---- P1a: zero borders ----
    if (t < 528) {                       // slab: 132 border cells x 4 chunks
        int ci_ = t >> 2, sub = t & 3;
        int cell;
        if (ci_ < 34)      cell = ci_;                    // ph = 0
        else if (ci_ < 68) cell = 33 * 34 + (ci_ - 34);   // ph = 33
        else { int k = ci_ - 68; cell = (1 + (k >> 1)) * 34 + (k & 1) * 33; }
        *(uint4*)(slab + cell * 64 + sub * 16) = uint4{0u, 0u, 0u, 0u};
    }
    if (t < 544) {                       // a2p: 68 border cells x 8 chunks
        int ci_ = t >> 3, sub = t & 7;
        int cell;
        if (ci_ < 18)      cell = ci_;                    // ph = 0
        else if (ci_ < 36) cell = 17 * 18 + (ci_ - 18);   // ph = 17
        else { int k = ci_ - 36; cell = (1 + (k >> 1)) * 18 + (k & 1) * 17; }
        *(uint4*)(a2p + cell * 128 + sub * 16) = uint4{0u, 0u, 0u, 0u};
    }

    // ---- P1b: x -> bn1+actq -> slab; bn_s -> asc (nt loads: x is 0-reuse) ----
#pragma unroll
    for (int it = 0; it < 4; ++it) {
        int u = t + it * 1024;           // 4096 units: (cq 0..15) x (wq 0..255)
        int wq = u & 255;
        int cq = u >> 8;
        int p0 = wq * 4;
        int h = p0 >> 5, w0 = p0 & 31;
        int c0 = cq * 4;
        float4 s1 = *(const float4*)(bnp + c0);
        float4 h1 = *(const float4*)(bnp + 64 + c0);
        float4 ssv = *(const float4*)(bnp + 128 + c0);
        float4 hsv = *(const float4*)(bnp + 192 + c0);
        const float* s1p = (const float*)&s1;
        const float* h1p = (const float*)&h1;
        const float* ssp = (const float*)&ssv;
        const float* hsp = (const float*)&hsv;
        f32x4 xr[4];
#pragma unroll
        for (int j = 0; j < 4; ++j)
            xr[j] = __builtin_nontemporal_load(
                (const f32x4*)(x + ((size_t)(n * 64 + c0 + j)) * 1024 + p0));
#pragma unroll
        for (int k = 0; k < 4; ++k) {
            unsigned u32 = 0;
#pragma unroll
            for (int j = 0; j < 4; ++j) {
                float xv = xr[j][k];
                float v = xv * s1p[j] + h1p[j];
                int q = (int)rintf(fminf(fmaxf(v, 0.f), 1.f) * 15.f);
                u32 |= (unsigned)q << (8 * j);
            }
            int pw = w0 + k + 1, ph = h + 1;
            int cell = ph * 34 + pw;
            int key = (pw >> 1) & 3;
            *(unsigned*)(slab + cell * 64 + (((cq >> 2) ^ key) * 16) + (cq & 3) * 4) = u32;
        }
        if ((h & 1) == 0) {
#pragma unroll
            for (int k = 0; k < 4; k += 2) {
                int w = w0 + k;
                __bf16 bv[4];
#pragma unroll
                for (int j = 0; j < 4; ++j) {
                    float xv = xr[j][k];
                    bv[j] = (__bf16)(xv * ssp[j] + hsp[j]);
                }
                int cell = (h >> 1) * 16 + (w >> 1);
                int key = (w >> 1) & 7;
                *(uint2*)(ascb + cell * 128 + (((cq >> 1) ^ key) * 16) + (cq & 1) * 8) =
                    *(uint2*)bv;
            }
        }
    }
    __syncthreads();

    const int wco = wv & 1;              // 2 co-tiles of 64
    const int wpos = wv >> 1;            // 8 pos-tiles (2 h2-rows x 16 w2)

    // ---- P2: conv1 (3x3 s2 p1, CIN=64, 9 K64-steps) -> a2p ----
    {
        i32x4 acc1[4][2] = {};
#pragma unroll
        for (int s = 0; s < 9; ++s) {
            const int kh = s / 3, kw = s % 3;
            i32x4 af[4];
#pragma unroll
            for (int i = 0; i < 4; ++i)
                af[i] = *(const i32x4*)(w1qi +
                    ((s * 128 + wco * 64 + i * 16 + lrow) * 64 + quad * 16));
            i32x4 bf[2];
#pragma unroll
            for (int j = 0; j < 2; ++j) {
                int h2 = wpos * 2 + j;
                int ph = 2 * h2 + kh;
                int pw = 2 * lrow + kw;
                int key = (pw >> 1) & 3;
                bf[j] = *(const i32x4*)(slab + (ph * 34 + pw) * 64 + ((quad ^ key) * 16));
            }
#pragma unroll
            for (int i = 0; i < 4; ++i)
#pragma unroll
                for (int j = 0; j < 2; ++j)
                    acc1[i][j] = __builtin_amdgcn_mfma_i32_16x16x64_i8(af[i], bf[j], acc1[i][j], 0, 0, 0);
        }
        // epilogue: bn2+actq -> a2p ints
#pragma unroll
        for (int i = 0; i < 4; ++i) {
            const int co0 = wco * 64 + i * 16 + quad * 4;
            float4 s2 = *(const float4*)(bnp + 256 + co0);
            float4 h2f = *(const float4*)(bnp + 384 + co0);
            const float* s2p = (const float*)&s2;
            const float* h2p = (const float*)&h2f;
#pragma unroll
            for (int j = 0; j < 2; ++j) {
                int h2 = wpos * 2 + j, w2 = lrow;
                unsigned u32 = 0;
#pragma unroll
                for (int r = 0; r < 4; ++r) {
                    float v = (float)acc1[i][j][r] * (s2p[r] * (1.f / 225.f)) + h2p[r];
                    int q = (int)rintf(fminf(fmaxf(v, 0.f), 1.f) * 15.f);
                    u32 |= (unsigned)q << (8 * r);
                }
                int cell = (h2 + 1) * 18 + (w2 + 1);
                int key = (w2 + 1) & 7;
                *(unsigned*)(a2p + cell * 128 + ((((co0 >> 4) ^ key)) * 16) + (co0 & 15)) = u32;
            }
        }
    }
    __syncthreads();

    // ---- P3: conv2 (3x3 s1 p1, CIN=128, 18 K64-steps) + bf16 shortcut ----
    {
        i32x4 acc2[4][2] = {};
#pragma unroll
        for (int s = 0; s < 18; ++s) {
            const int khw = s >> 1, cis = s & 1;
            const int kh = khw / 3, kw = khw % 3;
            i32x4 af[4];
#pragma unroll
            for (int i = 0; i < 4; ++i)
                af[i] = *(const i32x4*)(w2qi +
                    ((s * 128 + wco * 64 + i * 16 + lrow) * 64 + quad * 16));
            i32x4 bf[2];
#pragma unroll
            for (int j = 0; j < 2; ++j) {
                int h2 = wpos * 2 + j;
                int ph = h2 + kh, pw = lrow + kw;
                int chunk = cis * 4 + quad;
                int key = pw & 7;
                bf[j] = *(const i32x4*)(a2p + (ph * 18 + pw) * 128 + ((chunk ^ key) * 16));
            }
#pragma unroll
            for (int i = 0; i < 4; ++i)
#pragma unroll
                for (int j = 0; j < 2; ++j)
                    acc2[i][j] = __builtin_amdgcn_mfma_i32_16x16x64_i8(af[i], bf[j], acc2[i][j], 0, 0, 0);
        }
        f32x4 accM[4][2];
#pragma unroll
        for (int i = 0; i < 4; ++i)
#pragma unroll
            for (int j = 0; j < 2; ++j)
#pragma unroll
                for (int r = 0; r < 4; ++r)
                    accM[i][j][r] = (float)acc2[i][j][r] * (1.f / 225.f);
        // shortcut: 2 bf16 K32-steps from asc, C-in = accM
#pragma unroll
        for (int s = 0; s < 2; ++s) {
            bf16x8 af[4], bb[2];
#pragma unroll
            for (int i = 0; i < 4; ++i)
                af[i] = *(const bf16x8*)(wsq + (size_t)s * 4096 +
                    ((wco * 64 + i * 16 + lrow) * 32 + quad * 8));
#pragma unroll
            for (int j = 0; j < 2; ++j) {
                int h2 = wpos * 2 + j, w2 = lrow;
                int cell = h2 * 16 + w2;
                int sub = s * 4 + quad;
                bb[j] = *(const bf16x8*)(ascb + cell * 128 + ((sub ^ (w2 & 7)) * 16));
            }
#pragma unroll
            for (int i = 0; i < 4; ++i)
#pragma unroll
                for (int j = 0; j < 2; ++j)
                    accM[i][j] = __builtin_amdgcn_mfma_f32_16x16x32_bf16(af[i], bb[j], accM[i][j], 0, 0, 0);
        }
        // store out fp32 NCHW (nt: out is 0-reuse, keep it out of L2)
#pragma unroll
        for (int i = 0; i < 4; ++i) {
            const int co0 = wco * 64 + i * 16 + quad * 4;
#pragma unroll
            for (int j = 0; j < 2; ++j) {
                int pos = (wpos * 2 + j) * 16 + lrow;
#pragma unroll
                for (int r = 0; r < 4; ++r)
                    __builtin_nontemporal_store(accM[i][j][r],
                        out + ((size_t)n * 128 + co0 + r) * 256 + pos);
            }
        }
    }
}

extern "C" void kernel_launch(void* const* d_in, const int* in_sizes, int n_in,
                              void* d_out, int out_size, void* d_ws, size_t ws_size,
                              hipStream_t stream) {
    const float* x   = (const float*)d_in[0];
    const float* w1  = (const float*)d_in[1];
    const float* w2  = (const float*)d_in[2];
    const float* wsw = (const float*)d_in[3];
    const float* g1  = (const float*)d_in[4];
    const float* b1  = (const float*)d_in[5];
    const float* m1  = (const float*)d_in[6];
    const float* v1  = (const float*)d_in[7];
    const float* g2  = (const float*)d_in[8];
    const float* b2  = (const float*)d_in[9];
    const float* m2  = (const float*)d_in[10];
    const float* v2  = (const float*)d_in[11];
    const float* gs  = (const float*)d_in[12];
    const float* bs  = (const float*)d_in[13];
    const float* ms  = (const float*)d_in[14];
    const float* vs  = (const float*)d_in[15];
    float* out = (float*)d_out;
    char* ws = (char*)d_ws;

    // ws layout (bytes), ~256 KB total
    signed char* w1qi = (signed char*)(ws);                 // 73,728 i8
    signed char* w2qi = (signed char*)(ws + 73728);         // 147,456 i8
    __bf16*      wsq  = (__bf16*)(ws + 221184);             // 8,192 bf16
    float*       bnp  = (float*)(ws + 237568);              // 514 floats
    float*       wprt = (float*)(ws + 240128);              // 32 floats

    k_wmax<<<32, 256, 0, stream>>>(w1, w2, wprt);
    k_bnprep<<<1, 128, 0, stream>>>(g1, b1, m1, v1, g2, b2, m2, v2,
                                    gs, bs, ms, vs, wprt, bnp);
    k_wq_all<<<896, 256, 0, stream>>>(w1, w2, wsw, w1qi, w2qi, wsq, bnp);
    k_mega<<<256, 1024, 0, stream>>>(x, w1qi, w2qi, wsq, bnp, out);
}

// Round 19
// 48.557 us; speedup vs baseline: 1.6145x; 1.1929x over previous
//
#include <hip/hip_runtime.h>
#include <hip/hip_bf16.h>

// Wide_BasicBlock_Q: DoReFa-quantized residual block on MI355X (gfx950).
// Round 19: r18 mega-kernel + LDS-staged weights via dead-region reuse.
//   Theory: per-step weight fragments re-read from L2 by every wave are the
//   dominant serialized cost (~13µs chip-wide per convoy). Stage weights into
//   LDS regions that are dead at that point in the pipeline:
//     P1.5 computes the bf16 shortcut FIRST (accF in regs, 32 VGPR) -> ascb
//     region (32KB) freed -> P2 weight buffer (chunks of 4 steps).
//     After P2, slab (74KB) dead -> P3 weight buffer (9 steps per half).
//   Weight LDS reads are a per-wave bijection onto contiguous 1KB -> no
//   conflicts, layout identical to global. Epilogue: out = accI/225 + accF.

typedef __bf16 bf16x8 __attribute__((ext_vector_type(8)));
typedef float f32x4 __attribute__((ext_vector_type(4)));
typedef int i32x4 __attribute__((ext_vector_type(4)));

#define EPSV 1e-5f

// per-block partial max|w| -> wpart[b] (plain store, deterministic)
__global__ __launch_bounds__(256) void k_wmax(const float* __restrict__ w1,
                                              const float* __restrict__ w2,
                                              float* __restrict__ wpart) {
    int sel = blockIdx.x >> 4;                 // 0: w1, 1: w2
    const float* src = sel ? w2 : w1;
    int cnt = sel ? 128 * 128 * 9 : 128 * 64 * 9;
    float m = 0.f;
    for (int i = (blockIdx.x & 15) * 256 + threadIdx.x; i < cnt; i += 16 * 256)
        m = fmaxf(m, fabsf(src[i]));
#pragma unroll
    for (int off = 32; off > 0; off >>= 1)
        m = fmaxf(m, __shfl_down(m, off));
    __shared__ float red[4];
    if ((threadIdx.x & 63) == 0) red[threadIdx.x >> 6] = m;
    __syncthreads();
    if (threadIdx.x == 0)
        wpart[blockIdx.x] = fmaxf(fmaxf(red[0], red[1]), fmaxf(red[2], red[3]));
}

// bnp layout (floats): [0:64)=sc1 [64:128)=sh1 [128:192)=scs [192:256)=shs
// [256:384)=sc2 [384:512)=sh2 [512]=c1 [513]=c2  (c = 15/(2 tanh(max|w|)))
__global__ void k_bnprep(const float* g1, const float* b1, const float* m1, const float* v1,
                         const float* g2, const float* b2, const float* m2, const float* v2,
                         const float* gs, const float* bs, const float* ms, const float* vs,
                         const float* __restrict__ wpart, float* bnp) {
    int c = threadIdx.x;  // blockDim = 128
    if (c < 64) {
        float s = g1[c] * rsqrtf(v1[c] + EPSV);
        bnp[c] = s;          bnp[64 + c] = b1[c] - m1[c] * s;
        float s2 = gs[c] * rsqrtf(vs[c] + EPSV);
        bnp[128 + c] = s2;   bnp[192 + c] = bs[c] - ms[c] * s2;
    }
    float s = g2[c] * rsqrtf(v2[c] + EPSV);
    bnp[256 + c] = s;        bnp[384 + c] = b2[c] - m2[c] * s;
    if (c < 2) {
        float m = 0.f;
#pragma unroll
        for (int i = 0; i < 16; ++i) m = fmaxf(m, wpart[c * 16 + i]);
        bnp[512 + c] = 15.f / (2.f * tanhf(m));
    }
}

// All weight packs in one dispatch (grid 896):
//  b<288 : w1 -> i8 [(s*128+co)*64+kk], k=s*64+kk, k-order khw*64+ci
//  b<864 : w2 -> i8 same with CIN=128
//  else  : wsw -> bf16 [(s*128+co)*32+kk] (1x1: k=ci), unquantized
__global__ __launch_bounds__(256) void k_wq_all(
        const float* __restrict__ w1, const float* __restrict__ w2,
        const float* __restrict__ wsw,
        signed char* __restrict__ w1qi, signed char* __restrict__ w2qi,
        __bf16* __restrict__ wsq, const float* __restrict__ bnp) {
    int b = blockIdx.x, t = threadIdx.x;
    if (b < 864) {
        bool isw1 = b < 288;
        int idx = (isw1 ? b : b - 288) * 256 + t;
        float c = bnp[512 + (isw1 ? 0 : 1)];
        int kk = idx & 63;
        int co = (idx >> 6) & 127;
        int s = idx >> 13;
        int k = s * 64 + kk;
        int khw, ci;
        const float* src;
        if (isw1) { khw = k >> 6; ci = k & 63;  src = w1 + (co * 64 + ci) * 9 + khw; }
        else      { khw = k >> 7; ci = k & 127; src = w2 + (co * 128 + ci) * 9 + khw; }
        int j = (int)rintf(tanhf(*src) * c + 7.5f);
        (isw1 ? w1qi : w2qi)[idx] = (signed char)(2 * j - 15);
    } else {
        int idx = (b - 864) * 256 + t;
        int kk = idx & 31;
        int co = (idx >> 5) & 127;
        int s = idx >> 12;
        wsq[idx] = (__bf16)wsw[co * 64 + s * 32 + kk];
    }
}

// ---- mega kernel: one image per block ----
__global__ __launch_bounds__(1024, 4) void k_mega(
        const float* __restrict__ x,
        const signed char* __restrict__ w1qi,
        const signed char* __restrict__ w2qi,
        const __bf16* __restrict__ wsq,
        const float* __restrict__ bnp,
        float* __restrict__ out) {
    // LDS: slab 34*34*64 = 73984 | a2p 18*18*128 = 41472 | asc 256*128 = 32768
    __shared__ __align__(16) char lds_all[73984 + 41472 + 32768];
    signed char* slab = (signed char*)lds_all;
    signed char* a2p  = (signed char*)(lds_all + 73984);
    char*        ascb = lds_all + 73984 + 41472;

    const int t = threadIdx.x;
    const int n = blockIdx.x;
    const int wv = t >> 6, l = t & 63;
    const int lrow = l & 15, quad = l >> 4;
    const int wco = wv & 1;              // 2 co-tiles of 64
    const int wpos = wv >> 1;            // 8 pos-tiles (2 h2-rows x 16 w2)

    // ---- P1a: zero borders ----
    if (t < 528) {                       // slab: 132 border cells x 4 chunks
        int ci_ = t >> 2, sub = t & 3;
        int cell;
        if (ci_ < 34)      cell = ci_;                    // ph = 0
        else if (ci_ < 68) cell = 33 * 34 + (ci_ - 34);   // ph = 33
        else { int k = ci_ - 68; cell = (1 + (k >> 1)) * 34 + (k & 1) * 33; }
        *(uint4*)(slab + cell * 64 + sub * 16) = uint4{0u, 0u, 0u, 0u};
    }
    if (t < 544) {                       // a2p: 68 border cells x 8 chunks
        int ci_ = t >> 3, sub = t & 7;
        int cell;
        if (ci_ < 18)      cell = ci_;                    // ph = 0
        else if (ci_ < 36) cell = 17 * 18 + (ci_ - 18);   // ph = 17
        else { int k = ci_ - 36; cell = (1 + (k >> 1)) * 18 + (k & 1) * 17; }
        *(uint4*)(a2p + cell * 128 + sub * 16) = uint4{0u, 0u, 0u, 0u};
    }

    // ---- P1b: x -> bn1+actq -> slab; bn_s -> asc (nt loads: x is 0-reuse) ----
#pragma unroll
    for (int it = 0; it < 4; ++it) {
        int u = t + it * 1024;           // 4096 units: (cq 0..15) x (wq 0..255)
        int wq = u & 255;
        int cq = u >> 8;
        int p0 = wq * 4;
        int h = p0 >> 5, w0 = p0 & 31;
        int c0 = cq * 4;
        float4 s1 = *(const float4*)(bnp + c0);
        float4 h1 = *(const float4*)(bnp + 64 + c0);
        float4 ssv = *(const float4*)(bnp + 128 + c0);
        float4 hsv = *(const float4*)(bnp + 192 + c0);
        const float* s1p = (const float*)&s1;
        const float* h1p = (const float*)&h1;
        const float* ssp = (const float*)&ssv;
        const float* hsp = (const float*)&hsv;
        f32x4 xr[4];
#pragma unroll
        for (int j = 0; j < 4; ++j)
            xr[j] = __builtin_nontemporal_load(
                (const f32x4*)(x + ((size_t)(n * 64 + c0 + j)) * 1024 + p0));
#pragma unroll
        for (int k = 0; k < 4; ++k) {
            unsigned u32 = 0;
#pragma unroll
            for (int j = 0; j < 4; ++j) {
                float xv = xr[j][k];
                float v = xv * s1p[j] + h1p[j];
                int q = (int)rintf(fminf(fmaxf(v, 0.f), 1.f) * 15.f);
                u32 |= (unsigned)q << (8 * j);
            }
            int pw = w0 + k + 1, ph = h + 1;
            int cell = ph * 34 + pw;
            int key = (pw >> 1) & 3;
            *(unsigned*)(slab + cell * 64 + (((cq >> 2) ^ key) * 16) + (cq & 3) * 4) = u32;
        }
        if ((h & 1) == 0) {
#pragma unroll
            for (int k = 0; k < 4; k += 2) {
                int w = w0 + k;
                __bf16 bv[4];
#pragma unroll
                for (int j = 0; j < 4; ++j) {
                    float xv = xr[j][k];
                    bv[j] = (__bf16)(xv * ssp[j] + hsp[j]);
                }
                int cell = (h >> 1) * 16 + (w >> 1);
                int key = (w >> 1) & 7;
                *(uint2*)(ascb + cell * 128 + (((cq >> 1) ^ key) * 16) + (cq & 1) * 8) =
                    *(uint2*)bv;
            }
        }
    }
    __syncthreads();

    // ---- P1.5: bf16 shortcut FIRST (frees ascb for weight staging) ----
    f32x4 accF[4][2] = {};
#pragma unroll
    for (int s = 0; s < 2; ++s) {
        bf16x8 af[4], bb[2];
#pragma unroll
        for (int i = 0; i < 4; ++i)
            af[i] = *(const bf16x8*)(wsq + (size_t)s * 4096 +
                ((wco * 64 + i * 16 + lrow) * 32 + quad * 8));
#pragma unroll
        for (int j = 0; j < 2; ++j) {
            int cell = (wpos * 2 + j) * 16 + lrow;
            int sub = s * 4 + quad;
            bb[j] = *(const bf16x8*)(ascb + cell * 128 + ((sub ^ (lrow & 7)) * 16));
        }
#pragma unroll
        for (int i = 0; i < 4; ++i)
#pragma unroll
            for (int j = 0; j < 2; ++j)
                accF[i][j] = __builtin_amdgcn_mfma_f32_16x16x32_bf16(af[i], bb[j], accF[i][j], 0, 0, 0);
    }
    __syncthreads();                     // ascb reads done -> reusable

    // ---- P2: conv1 (3x3 s2 p1, 9 K64-steps), weights staged in ascb ----
    {
        char* wlds2 = ascb;              // 32KB = 4 steps x 8KB
        i32x4 acc1[4][2] = {};
#pragma unroll 1
        for (int chunk = 0; chunk < 3; ++chunk) {
            const int s0 = chunk * 4;
            const int ns = (chunk == 2) ? 1 : 4;
            for (int c = t; c < ns * 512; c += 1024)
                *(uint4*)(wlds2 + c * 16) =
                    *(const uint4*)(w1qi + (size_t)s0 * 8192 + c * 16);
            __syncthreads();             // weights staged
#pragma unroll 1
            for (int sl = 0; sl < ns; ++sl) {
                const int s = s0 + sl;
                const int kh = (s * 11) >> 5, kw = s - 3 * kh;
                i32x4 af[4];
#pragma unroll
                for (int i = 0; i < 4; ++i)
                    af[i] = *(const i32x4*)(wlds2 +
                        ((sl * 128 + wco * 64 + i * 16 + lrow) * 64 + quad * 16));
                i32x4 bf[2];
#pragma unroll
                for (int j = 0; j < 2; ++j) {
                    int h2 = wpos * 2 + j;
                    int ph = 2 * h2 + kh;
                    int pw = 2 * lrow + kw;
                    int key = (pw >> 1) & 3;
                    bf[j] = *(const i32x4*)(slab + (ph * 34 + pw) * 64 + ((quad ^ key) * 16));
                }
#pragma unroll
                for (int i = 0; i < 4; ++i)
#pragma unroll
                    for (int j = 0; j < 2; ++j)
                        acc1[i][j] = __builtin_amdgcn_mfma_i32_16x16x64_i8(af[i], bf[j], acc1[i][j], 0, 0, 0);
            }
            __syncthreads();             // WAR: reads done before restage
        }
        // epilogue: bn2+actq -> a2p ints
#pragma unroll
        for (int i = 0; i < 4; ++i) {
            const int co0 = wco * 64 + i * 16 + quad * 4;
            float4 s2 = *(const float4*)(bnp + 256 + co0);
            float4 h2f = *(const float4*)(bnp + 384 + co0);
            const float* s2p = (const float*)&s2;
            const float* h2p = (const float*)&h2f;
#pragma unroll
            for (int j = 0; j < 2; ++j) {
                int h2 = wpos * 2 + j, w2 = lrow;
                unsigned u32 = 0;
#pragma unroll
                for (int r = 0; r < 4; ++r) {
                    float v = (float)acc1[i][j][r] * (s2p[r] * (1.f / 225.f)) + h2p[r];
                    int q = (int)rintf(fminf(fmaxf(v, 0.f), 1.f) * 15.f);
                    u32 |= (unsigned)q << (8 * r);
                }
                int cell = (h2 + 1) * 18 + (w2 + 1);
                int key = (w2 + 1) & 7;
                *(unsigned*)(a2p + cell * 128 + ((((co0 >> 4) ^ key)) * 16) + (co0 & 15)) = u32;
            }
        }
    }

    // ---- P3: conv2 (3x3 s1 p1, 18 K64-steps), weights staged in slab ----
    {
        char* wlds3 = (char*)slab;       // 74KB >= 9 steps x 8KB
        i32x4 acc2[4][2] = {};
#pragma unroll 1
        for (int half = 0; half < 2; ++half) {
            const signed char* src = w2qi + (size_t)half * 73728;
            // stage 9 steps = 4608 x 16B (also covers a2p-write visibility
            // for half 0 via the barrier below)
            for (int c = t; c < 4608; c += 1024)
                *(uint4*)(wlds3 + c * 16) = *(const uint4*)(src + c * 16);
            __syncthreads();             // weights staged (+ a2p visible)
#pragma unroll 1
            for (int sl = 0; sl < 9; ++sl) {
                const int s = half * 9 + sl;
                const int khw = s >> 1, cis = s & 1;
                const int kh = (khw * 11) >> 5, kw = khw - 3 * kh;
                i32x4 af[4];
#pragma unroll
                for (int i = 0; i < 4; ++i)
                    af[i] = *(const i32x4*)(wlds3 +
                        ((sl * 128 + wco * 64 + i * 16 + lrow) * 64 + quad * 16));
                i32x4 bf[2];
#pragma unroll
                for (int j = 0; j < 2; ++j) {
                    int h2 = wpos * 2 + j;
                    int ph = h2 + kh, pw = lrow + kw;
                    int chunkk = cis * 4 + quad;
                    int key = pw & 7;
                    bf[j] = *(const i32x4*)(a2p + (ph * 18 + pw) * 128 + ((chunkk ^ key) * 16));
                }
#pragma unroll
                for (int i = 0; i < 4; ++i)
#pragma unroll
                    for (int j = 0; j < 2; ++j)
                        acc2[i][j] = __builtin_amdgcn_mfma_i32_16x16x64_i8(af[i], bf[j], acc2[i][j], 0, 0, 0);
            }
            __syncthreads();             // WAR before restage
        }
        // epilogue: accI/225 + shortcut; nt-store fp32 NCHW
#pragma unroll
        for (int i = 0; i < 4; ++i) {
            const int co0 = wco * 64 + i * 16 + quad * 4;
#pragma unroll
            for (int j = 0; j < 2; ++j) {
                int pos = (wpos * 2 + j) * 16 + lrow;
#pragma unroll
                for (int r = 0; r < 4; ++r) {
                    float v = (float)acc2[i][j][r] * (1.f / 225.f) + accF[i][j][r];
                    __builtin_nontemporal_store(v,
                        out + ((size_t)n * 128 + co0 + r) * 256 + pos);
                }
            }
        }
    }
}

extern "C" void kernel_launch(void* const* d_in, const int* in_sizes, int n_in,
                              void* d_out, int out_size, void* d_ws, size_t ws_size,
                              hipStream_t stream) {
    const float* x   = (const float*)d_in[0];
    const float* w1  = (const float*)d_in[1];
    const float* w2  = (const float*)d_in[2];
    const float* wsw = (const float*)d_in[3];
    const float* g1  = (const float*)d_in[4];
    const float* b1  = (const float*)d_in[5];
    const float* m1  = (const float*)d_in[6];
    const float* v1  = (const float*)d_in[7];
    const float* g2  = (const float*)d_in[8];
    const float* b2  = (const float*)d_in[9];
    const float* m2  = (const float*)d_in[10];
    const float* v2  = (const float*)d_in[11];
    const float* gs  = (const float*)d_in[12];
    const float* bs  = (const float*)d_in[13];
    const float* ms  = (const float*)d_in[14];
    const float* vs  = (const float*)d_in[15];
    float* out = (float*)d_out;
    char* ws = (char*)d_ws;

    // ws layout (bytes), ~256 KB total
    signed char* w1qi = (signed char*)(ws);                 // 73,728 i8
    signed char* w2qi = (signed char*)(ws + 73728);         // 147,456 i8
    __bf16*      wsq  = (__bf16*)(ws + 221184);             // 8,192 bf16
    float*       bnp  = (float*)(ws + 237568);              // 514 floats
    float*       wprt = (float*)(ws + 240128);              // 32 floats

    k_wmax<<<32, 256, 0, stream>>>(w1, w2, wprt);
    k_bnprep<<<1, 128, 0, stream>>>(g1, b1, m1, v1, g2, b2, m2, v2,
                                    gs, bs, ms, vs, wprt, bnp);
    k_wq_all<<<896, 256, 0, stream>>>(w1, w2, wsw, w1qi, w2qi, wsq, bnp);
    k_mega<<<256, 1024, 0, stream>>>(x, w1qi, w2qi, wsq, bnp, out);
}

// Round 20
// 46.659 us; speedup vs baseline: 1.6802x; 1.0407x over previous
//
#include <hip/hip_runtime.h>
#include <hip/hip_bf16.h>

// Wide_BasicBlock_Q: DoReFa-quantized residual block on MI355X (gfx950).
// Round 20: r19 (LDS-staged weights via dead-region reuse) + two latency fixes:
//   1) P1 x-loads batched 8-deep (two named f32x4[4] arrays loaded before any
//      conversion) -> 2x outstanding bytes on the x stream.
//   2) P3 half-0 weight staging split T14-style: global loads issued to regs
//      BEFORE the P2 epilogue, ds_write after it (latency hidden under the
//      epilogue's VALU + a2p writes).
//   Everything else identical to the passing r19 (absmax 0.5).

typedef __bf16 bf16x8 __attribute__((ext_vector_type(8)));
typedef float f32x4 __attribute__((ext_vector_type(4)));
typedef int i32x4 __attribute__((ext_vector_type(4)));

#define EPSV 1e-5f

// per-block partial max|w| -> wpart[b] (plain store, deterministic)
__global__ __launch_bounds__(256) void k_wmax(const float* __restrict__ w1,
                                              const float* __restrict__ w2,
                                              float* __restrict__ wpart) {
    int sel = blockIdx.x >> 4;                 // 0: w1, 1: w2
    const float* src = sel ? w2 : w1;
    int cnt = sel ? 128 * 128 * 9 : 128 * 64 * 9;
    float m = 0.f;
    for (int i = (blockIdx.x & 15) * 256 + threadIdx.x; i < cnt; i += 16 * 256)
        m = fmaxf(m, fabsf(src[i]));
#pragma unroll
    for (int off = 32; off > 0; off >>= 1)
        m = fmaxf(m, __shfl_down(m, off));
    __shared__ float red[4];
    if ((threadIdx.x & 63) == 0) red[threadIdx.x >> 6] = m;
    __syncthreads();
    if (threadIdx.x == 0)
        wpart[blockIdx.x] = fmaxf(fmaxf(red[0], red[1]), fmaxf(red[2], red[3]));
}

// bnp layout (floats): [0:64)=sc1 [64:128)=sh1 [128:192)=scs [192:256)=shs
// [256:384)=sc2 [384:512)=sh2 [512]=c1 [513]=c2  (c = 15/(2 tanh(max|w|)))
__global__ void k_bnprep(const float* g1, const float* b1, const float* m1, const float* v1,
                         const float* g2, const float* b2, const float* m2, const float* v2,
                         const float* gs, const float* bs, const float* ms, const float* vs,
                         const float* __restrict__ wpart, float* bnp) {
    int c = threadIdx.x;  // blockDim = 128
    if (c < 64) {
        float s = g1[c] * rsqrtf(v1[c] + EPSV);
        bnp[c] = s;          bnp[64 + c] = b1[c] - m1[c] * s;
        float s2 = gs[c] * rsqrtf(vs[c] + EPSV);
        bnp[128 + c] = s2;   bnp[192 + c] = bs[c] - ms[c] * s2;
    }
    float s = g2[c] * rsqrtf(v2[c] + EPSV);
    bnp[256 + c] = s;        bnp[384 + c] = b2[c] - m2[c] * s;
    if (c < 2) {
        float m = 0.f;
#pragma unroll
        for (int i = 0; i < 16; ++i) m = fmaxf(m, wpart[c * 16 + i]);
        bnp[512 + c] = 15.f / (2.f * tanhf(m));
    }
}

// All weight packs in one dispatch (grid 896):
//  b<288 : w1 -> i8 [(s*128+co)*64+kk], k=s*64+kk, k-order khw*64+ci
//  b<864 : w2 -> i8 same with CIN=128
//  else  : wsw -> bf16 [(s*128+co)*32+kk] (1x1: k=ci), unquantized
__global__ __launch_bounds__(256) void k_wq_all(
        const float* __restrict__ w1, const float* __restrict__ w2,
        const float* __restrict__ wsw,
        signed char* __restrict__ w1qi, signed char* __restrict__ w2qi,
        __bf16* __restrict__ wsq, const float* __restrict__ bnp) {
    int b = blockIdx.x, t = threadIdx.x;
    if (b < 864) {
        bool isw1 = b < 288;
        int idx = (isw1 ? b : b - 288) * 256 + t;
        float c = bnp[512 + (isw1 ? 0 : 1)];
        int kk = idx & 63;
        int co = (idx >> 6) & 127;
        int s = idx >> 13;
        int k = s * 64 + kk;
        int khw, ci;
        const float* src;
        if (isw1) { khw = k >> 6; ci = k & 63;  src = w1 + (co * 64 + ci) * 9 + khw; }
        else      { khw = k >> 7; ci = k & 127; src = w2 + (co * 128 + ci) * 9 + khw; }
        int j = (int)rintf(tanhf(*src) * c + 7.5f);
        (isw1 ? w1qi : w2qi)[idx] = (signed char)(2 * j - 15);
    } else {
        int idx = (b - 864) * 256 + t;
        int kk = idx & 31;
        int co = (idx >> 5) & 127;
        int s = idx >> 12;
        wsq[idx] = (__bf16)wsw[co * 64 + s * 32 + kk];
    }
}

// ---- mega kernel: one image per block ----
__global__ __launch_bounds__(1024, 4) void k_mega(
        const float* __restrict__ x,
        const signed char* __restrict__ w1qi,
        const signed char* __restrict__ w2qi,
        const __bf16* __restrict__ wsq,
        const float* __restrict__ bnp,
        float* __restrict__ out) {
    // LDS: slab 34*34*64 = 73984 | a2p 18*18*128 = 41472 | asc 256*128 = 32768
    __shared__ __align__(16) char lds_all[73984 + 41472 + 32768];
    signed char* slab = (signed char*)lds_all;
    signed char* a2p  = (signed char*)(lds_all + 73984);
    char*        ascb = lds_all + 73984 + 41472;

    const int t = threadIdx.x;
    const int n = blockIdx.x;
    const int wv = t >> 6, l = t & 63;
    const int lrow = l & 15, quad = l >> 4;
    const int wco = wv & 1;              // 2 co-tiles of 64
    const int wpos = wv >> 1;            // 8 pos-tiles (2 h2-rows x 16 w2)

    // ---- P1a: zero borders ----
    if (t < 528) {                       // slab: 132 border cells x 4 chunks
        int ci_ = t >> 2, sub = t & 3;
        int cell;
        if (ci_ < 34)      cell = ci_;                    // ph = 0
        else if (ci_ < 68) cell = 33 * 34 + (ci_ - 34);   // ph = 33
        else { int k = ci_ - 68; cell = (1 + (k >> 1)) * 34 + (k & 1) * 33; }
        *(uint4*)(slab + cell * 64 + sub * 16) = uint4{0u, 0u, 0u, 0u};
    }
    if (t < 544) {                       // a2p: 68 border cells x 8 chunks
        int ci_ = t >> 3, sub = t & 7;
        int cell;
        if (ci_ < 18)      cell = ci_;                    // ph = 0
        else if (ci_ < 36) cell = 17 * 18 + (ci_ - 18);   // ph = 17
        else { int k = ci_ - 36; cell = (1 + (k >> 1)) * 18 + (k & 1) * 17; }
        *(uint4*)(a2p + cell * 128 + sub * 16) = uint4{0u, 0u, 0u, 0u};
    }

    // ---- P1b: x -> bn1+actq -> slab; bn_s -> asc ----
    // 8-deep load batching: two units' loads (8x f32x4) issued before any
    // conversion (nt loads: x is 0-reuse).
    auto proc = [&](int u, f32x4* xr) {
        int wq = u & 255;
        int cq = u >> 8;
        int p0 = wq * 4;
        int h = p0 >> 5, w0 = p0 & 31;
        int c0 = cq * 4;
        float4 s1 = *(const float4*)(bnp + c0);
        float4 h1 = *(const float4*)(bnp + 64 + c0);
        const float* s1p = (const float*)&s1;
        const float* h1p = (const float*)&h1;
#pragma unroll
        for (int k = 0; k < 4; ++k) {
            unsigned u32 = 0;
#pragma unroll
            for (int j = 0; j < 4; ++j) {
                float xv = xr[j][k];
                float v = xv * s1p[j] + h1p[j];
                int q = (int)rintf(fminf(fmaxf(v, 0.f), 1.f) * 15.f);
                u32 |= (unsigned)q << (8 * j);
            }
            int pw = w0 + k + 1, ph = h + 1;
            int cell = ph * 34 + pw;
            int key = (pw >> 1) & 3;
            *(unsigned*)(slab + cell * 64 + (((cq >> 2) ^ key) * 16) + (cq & 3) * 4) = u32;
        }
        if ((h & 1) == 0) {
            float4 ssv = *(const float4*)(bnp + 128 + c0);
            float4 hsv = *(const float4*)(bnp + 192 + c0);
            const float* ssp = (const float*)&ssv;
            const float* hsp = (const float*)&hsv;
#pragma unroll
            for (int k = 0; k < 4; k += 2) {
                int w = w0 + k;
                __bf16 bv[4];
#pragma unroll
                for (int j = 0; j < 4; ++j) {
                    float xv = xr[j][k];
                    bv[j] = (__bf16)(xv * ssp[j] + hsp[j]);
                }
                int cell = (h >> 1) * 16 + (w >> 1);
                int key = (w >> 1) & 7;
                *(uint2*)(ascb + cell * 128 + (((cq >> 1) ^ key) * 16) + (cq & 1) * 8) =
                    *(uint2*)bv;
            }
        }
    };
#pragma unroll
    for (int pr = 0; pr < 2; ++pr) {
        const int uA = t + (2 * pr) * 1024;
        const int uB = uA + 1024;
        const int p0A = (uA & 255) * 4, c0A = (uA >> 8) * 4;
        const int p0B = (uB & 255) * 4, c0B = (uB >> 8) * 4;
        f32x4 xrA[4], xrB[4];
#pragma unroll
        for (int j = 0; j < 4; ++j)
            xrA[j] = __builtin_nontemporal_load(
                (const f32x4*)(x + ((size_t)(n * 64 + c0A + j)) * 1024 + p0A));
#pragma unroll
        for (int j = 0; j < 4; ++j)
            xrB[j] = __builtin_nontemporal_load(
                (const f32x4*)(x + ((size_t)(n * 64 + c0B + j)) * 1024 + p0B));
        proc(uA, xrA);
        proc(uB, xrB);
    }
    __syncthreads();

    // ---- P1.5: bf16 shortcut FIRST (frees ascb for weight staging) ----
    f32x4 accF[4][2] = {};
#pragma unroll
    for (int s = 0; s < 2; ++s) {
        bf16x8 af[4], bb[2];
#pragma unroll
        for (int i = 0; i < 4; ++i)
            af[i] = *(const bf16x8*)(wsq + (size_t)s * 4096 +
                ((wco * 64 + i * 16 + lrow) * 32 + quad * 8));
#pragma unroll
        for (int j = 0; j < 2; ++j) {
            int cell = (wpos * 2 + j) * 16 + lrow;
            int sub = s * 4 + quad;
            bb[j] = *(const bf16x8*)(ascb + cell * 128 + ((sub ^ (lrow & 7)) * 16));
        }
#pragma unroll
        for (int i = 0; i < 4; ++i)
#pragma unroll
            for (int j = 0; j < 2; ++j)
                accF[i][j] = __builtin_amdgcn_mfma_f32_16x16x32_bf16(af[i], bb[j], accF[i][j], 0, 0, 0);
    }
    __syncthreads();                     // ascb reads done -> reusable

    // ---- P2: conv1 (3x3 s2 p1, 9 K64-steps), weights staged in ascb ----
    i32x4 acc1[4][2] = {};
    {
        char* wlds2 = ascb;              // 32KB = 4 steps x 8KB
#pragma unroll 1
        for (int chunk = 0; chunk < 3; ++chunk) {
            const int s0 = chunk * 4;
            const int ns = (chunk == 2) ? 1 : 4;
            for (int c = t; c < ns * 512; c += 1024)
                *(uint4*)(wlds2 + c * 16) =
                    *(const uint4*)(w1qi + (size_t)s0 * 8192 + c * 16);
            __syncthreads();             // weights staged
#pragma unroll 1
            for (int sl = 0; sl < ns; ++sl) {
                const int s = s0 + sl;
                const int kh = (s * 11) >> 5, kw = s - 3 * kh;
                i32x4 af[4];
#pragma unroll
                for (int i = 0; i < 4; ++i)
                    af[i] = *(const i32x4*)(wlds2 +
                        ((sl * 128 + wco * 64 + i * 16 + lrow) * 64 + quad * 16));
                i32x4 bf[2];
#pragma unroll
                for (int j = 0; j < 2; ++j) {
                    int h2 = wpos * 2 + j;
                    int ph = 2 * h2 + kh;
                    int pw = 2 * lrow + kw;
                    int key = (pw >> 1) & 3;
                    bf[j] = *(const i32x4*)(slab + (ph * 34 + pw) * 64 + ((quad ^ key) * 16));
                }
#pragma unroll
                for (int i = 0; i < 4; ++i)
#pragma unroll
                    for (int j = 0; j < 2; ++j)
                        acc1[i][j] = __builtin_amdgcn_mfma_i32_16x16x64_i8(af[i], bf[j], acc1[i][j], 0, 0, 0);
            }
            __syncthreads();             // WAR: reads done before restage
        }
    }

    // ---- T14 async-stage: issue P3 half-0 weight loads BEFORE P2 epilogue ----
    // (slab reads all done at the last barrier above; ds_writes happen after
    //  the epilogue, so the ~500cy global latency hides under it)
    char* wlds3 = (char*)slab;           // 74KB >= 9 steps x 8KB
    uint4 wr0 = *(const uint4*)(w2qi + (size_t)t * 16);
    uint4 wr1 = *(const uint4*)(w2qi + (size_t)(t + 1024) * 16);
    uint4 wr2 = *(const uint4*)(w2qi + (size_t)(t + 2048) * 16);
    uint4 wr3 = *(const uint4*)(w2qi + (size_t)(t + 3072) * 16);
    uint4 wr4 = {0u, 0u, 0u, 0u};
    const bool has4 = t < 512;           // 4608 chunks total
    if (has4) wr4 = *(const uint4*)(w2qi + (size_t)(t + 4096) * 16);

    // ---- P2 epilogue: bn2+actq -> a2p ints ----
#pragma unroll
    for (int i = 0; i < 4; ++i) {
        const int co0 = wco * 64 + i * 16 + quad * 4;
        float4 s2 = *(const float4*)(bnp + 256 + co0);
        float4 h2f = *(const float4*)(bnp + 384 + co0);
        const float* s2p = (const float*)&s2;
        const float* h2p = (const float*)&h2f;
#pragma unroll
        for (int j = 0; j < 2; ++j) {
            int h2 = wpos * 2 + j, w2c = lrow;
            unsigned u32 = 0;
#pragma unroll
            for (int r = 0; r < 4; ++r) {
                float v = (float)acc1[i][j][r] * (s2p[r] * (1.f / 225.f)) + h2p[r];
                int q = (int)rintf(fminf(fmaxf(v, 0.f), 1.f) * 15.f);
                u32 |= (unsigned)q << (8 * r);
            }
            int cell = (h2 + 1) * 18 + (w2c + 1);
            int key = (w2c + 1) & 7;
            *(unsigned*)(a2p + cell * 128 + ((((co0 >> 4) ^ key)) * 16) + (co0 & 15)) = u32;
        }
    }

    // ---- write staged half-0 weights to slab ----
    *(uint4*)(wlds3 + (size_t)t * 16) = wr0;
    *(uint4*)(wlds3 + (size_t)(t + 1024) * 16) = wr1;
    *(uint4*)(wlds3 + (size_t)(t + 2048) * 16) = wr2;
    *(uint4*)(wlds3 + (size_t)(t + 3072) * 16) = wr3;
    if (has4) *(uint4*)(wlds3 + (size_t)(t + 4096) * 16) = wr4;
    __syncthreads();                     // weights staged + a2p visible

    // ---- P3: conv2 (3x3 s1 p1, 18 K64-steps), weights staged in slab ----
    {
        i32x4 acc2[4][2] = {};
#pragma unroll 1
        for (int half = 0; half < 2; ++half) {
            if (half == 1) {
                __syncthreads();         // WAR: half-0 weight reads done
                for (int c = t; c < 4608; c += 1024)
                    *(uint4*)(wlds3 + (size_t)c * 16) =
                        *(const uint4*)(w2qi + 73728 + (size_t)c * 16);
                __syncthreads();         // half-1 weights staged
            }
#pragma unroll 1
            for (int sl = 0; sl < 9; ++sl) {
                const int s = half * 9 + sl;
                const int khw = s >> 1, cis = s & 1;
                const int kh = (khw * 11) >> 5, kw = khw - 3 * kh;
                i32x4 af[4];
#pragma unroll
                for (int i = 0; i < 4; ++i)
                    af[i] = *(const i32x4*)(wlds3 +
                        ((sl * 128 + wco * 64 + i * 16 + lrow) * 64 + quad * 16));
                i32x4 bf[2];
#pragma unroll
                for (int j = 0; j < 2; ++j) {
                    int h2 = wpos * 2 + j;
                    int ph = h2 + kh, pw = lrow + kw;
                    int chunkk = cis * 4 + quad;
                    int key = pw & 7;
                    bf[j] = *(const i32x4*)(a2p + (ph * 18 + pw) * 128 + ((chunkk ^ key) * 16));
                }
#pragma unroll
                for (int i = 0; i < 4; ++i)
#pragma unroll
                    for (int j = 0; j < 2; ++j)
                        acc2[i][j] = __builtin_amdgcn_mfma_i32_16x16x64_i8(af[i], bf[j], acc2[i][j], 0, 0, 0);
            }
        }
        // epilogue: accI/225 + shortcut; nt-store fp32 NCHW
#pragma unroll
        for (int i = 0; i < 4; ++i) {
            const int co0 = wco * 64 + i * 16 + quad * 4;
#pragma unroll
            for (int j = 0; j < 2; ++j) {
                int pos = (wpos * 2 + j) * 16 + lrow;
#pragma unroll
                for (int r = 0; r < 4; ++r) {
                    float v = (float)acc2[i][j][r] * (1.f / 225.f) + accF[i][j][r];
                    __builtin_nontemporal_store(v,
                        out + ((size_t)n * 128 + co0 + r) * 256 + pos);
                }
            }
        }
    }
}

extern "C" void kernel_launch(void* const* d_in, const int* in_sizes, int n_in,
                              void* d_out, int out_size, void* d_ws, size_t ws_size,
                              hipStream_t stream) {
    const float* x   = (const float*)d_in[0];
    const float* w1  = (const float*)d_in[1];
    const float* w2  = (const float*)d_in[2];
    const float* wsw = (const float*)d_in[3];
    const float* g1  = (const float*)d_in[4];
    const float* b1  = (const float*)d_in[5];
    const float* m1  = (const float*)d_in[6];
    const float* v1  = (const float*)d_in[7];
    const float* g2  = (const float*)d_in[8];
    const float* b2  = (const float*)d_in[9];
    const float* m2  = (const float*)d_in[10];
    const float* v2  = (const float*)d_in[11];
    const float* gs  = (const float*)d_in[12];
    const float* bs  = (const float*)d_in[13];
    const float* ms  = (const float*)d_in[14];
    const float* vs  = (const float*)d_in[15];
    float* out = (float*)d_out;
    char* ws = (char*)d_ws;

    // ws layout (bytes), ~256 KB total
    signed char* w1qi = (signed char*)(ws);                 // 73,728 i8
    signed char* w2qi = (signed char*)(ws + 73728);         // 147,456 i8
    __bf16*      wsq  = (__bf16*)(ws + 221184);             // 8,192 bf16
    float*       bnp  = (float*)(ws + 237568);              // 514 floats
    float*       wprt = (float*)(ws + 240128);              // 32 floats

    k_wmax<<<32, 256, 0, stream>>>(w1, w2, wprt);
    k_bnprep<<<1, 128, 0, stream>>>(g1, b1, m1, v1, g2, b2, m2, v2,
                                    gs, bs, ms, vs, wprt, bnp);
    k_wq_all<<<896, 256, 0, stream>>>(w1, w2, wsw, w1qi, w2qi, wsq, bnp);
    k_mega<<<256, 1024, 0, stream>>>(x, w1qi, w2qi, wsq, bnp, out);
}